// Round 17
// baseline (217.782 us; speedup 1.0000x reference)
//
#include <hip/hip_runtime.h>
#include <hip/hip_bf16.h>
#include <stdint.h>

#define WIDTH 4096
#define NROWS 8192
#define NHEADS 8
#define BW 512
#define CS 128
#define NCHUNK (NROWS/CS)
#define LOG2E 1.4426950408889634f

typedef short bf16x8 __attribute__((ext_vector_type(8)));
typedef float f32x4 __attribute__((ext_vector_type(4)));

__device__ __forceinline__ uint32_t rne_bf16(float f) {
  uint32_t u = __float_as_uint(f);
  return (u + 0x7fffu + ((u >> 16) & 1u)) >> 16;
}
__device__ __forceinline__ float bf16_to_f32(uint32_t bits) {
  return __uint_as_float(bits << 16);
}
__device__ __forceinline__ uint32_t cvtpk(float a, float b) {
  uint32_t r;
  asm("v_cvt_pk_bf16_f32 %0, %1, %2" : "=v"(r) : "v"(a), "v"(b));
  return r;
}

__device__ __forceinline__ void gload_lds16(const void* g, void* l) {
  __builtin_amdgcn_global_load_lds(
      (const __attribute__((address_space(1))) void*)g,
      (__attribute__((address_space(3))) void*)l, 16, 0, 0);
}

// ---- fused prep, balanced blocks: weights transpose(+log2e) / x->bf16 / cvec2
__global__ void prep_all(const float* __restrict__ x, uint16_t* __restrict__ xb,
                         const float* __restrict__ ig_w, const float* __restrict__ ag_w,
                         uint16_t* __restrict__ wt,
                         const float* __restrict__ a_param, float* __restrict__ cvec2) {
  __shared__ float tile[32][33];
  const int b = blockIdx.x;
  const int tid = threadIdx.x;
  if (b < 4096) {
    // weights: f32 [h][i][j] -> bf16 [g*8+h][j][i], scaled by log2e
    int m  = b >> 8;
    int j0 = ((b >> 4) & 15) * 32;
    int i0 = (b & 15) * 32;
    const float* src = ((m >> 3) ? ag_w : ig_w) + (size_t)(m & 7) * BW * BW;
    int tx = tid & 31, ty = tid >> 5;
    #pragma unroll
    for (int k = 0; k < 4; k++) {
      int i = i0 + ty + 8 * k;
      tile[ty + 8 * k][tx] = src[(size_t)i * BW + (j0 + tx)] * LOG2E;
    }
    __syncthreads();
    #pragma unroll
    for (int k = 0; k < 4; k++) {
      int j = j0 + ty + 8 * k;
      wt[((size_t)m * BW + j) * BW + (i0 + tx)] = (uint16_t)rne_bf16(tile[tx][ty + 8 * k]);
    }
  } else if (b < 12288) {
    // x -> bf16: 16 floats per thread, one shot
    size_t i = ((size_t)(b - 4096) * 256 + tid) * 16;
    float4 f0 = *reinterpret_cast<const float4*>(x + i);
    float4 f1 = *reinterpret_cast<const float4*>(x + i + 4);
    float4 f2 = *reinterpret_cast<const float4*>(x + i + 8);
    float4 f3 = *reinterpret_cast<const float4*>(x + i + 12);
    uint4 v0, v1;
    v0.x = cvtpk(f0.x, f0.y); v0.y = cvtpk(f0.z, f0.w);
    v0.z = cvtpk(f1.x, f1.y); v0.w = cvtpk(f1.z, f1.w);
    v1.x = cvtpk(f2.x, f2.y); v1.y = cvtpk(f2.z, f2.w);
    v1.z = cvtpk(f3.x, f3.y); v1.w = cvtpk(f3.z, f3.w);
    *reinterpret_cast<uint4*>(xb + i) = v0;
    *reinterpret_cast<uint4*>(xb + i + 8) = v1;
  } else {
    int i = (b - 12288) * 256 + tid;
    if (i < WIDTH) {
      float v = a_param[i];
      float sp = (v > 15.f) ? v : log1pf(expf(v));
      cvec2[i] = 8.f * sp * LOG2E;
    }
  }
}

// ---- GEMM: dual-gate bf16 MFMA, tile 128x64, BK=32, 256 thr.
//      Fully unrolled 16-step K-loop: buffer offsets and swizzle selects are
//      compile-time; fragment addresses precomputed once (ds_read offset:
//      immediates). Issue-early staging, one barrier/step, setprio, rotated
//      K order (mod 16) so output X sub-slices end resident in buf0/buf1.
#define BM 128
#define BN 64
#define BK 32
// buf k at dsm + k*16384: X [128 rows x 64B] @ +0, W [2][64 rows x 64B] @ +8192
// 64B rows: chunk swizzle s(row) = (row>>1)&3 applied to byte bits 4-5.

__global__ __launch_bounds__(256, 4)
void gates_gemm(const uint16_t* __restrict__ xb,
                const int* __restrict__ s,
                const uint16_t* __restrict__ wt,
                const float* __restrict__ ig_b,
                const float* __restrict__ ag_b,
                const float* __restrict__ cvec2,
                uint32_t* __restrict__ lanx,
                float* __restrict__ cA,
                float* __restrict__ cB) {
  __shared__ __align__(16) unsigned char dsm[32768];
  __shared__ unsigned char resetm[BM];

  const int b = blockIdx.x;                    // 0..4095
  const int orig = (b & 7) * 512 + (b >> 3);   // XCD-chunked: one head per XCD
  const int h  = orig >> 9;
  const int rem = orig & 511;
  const int mt = rem >> 3;                     // 0..63
  const int nt = rem & 7;                      // 0..7
  const int m0 = mt * BM;
  const int j0 = nt * BN;

  const int tid = threadIdx.x;
  const int lane = tid & 63;
  const int w = tid >> 6;       // 0..3
  const int wr = w >> 1;        // 0..1 (M: 64-row halves)
  const int wc = w & 1;         // 0..1 (N: 32-col halves)
  const int lrow = lane & 15;
  const int lkg  = lane >> 4;

  if (tid < BM) {
    int n = m0 + tid;
    resetm[tid] = (n == 0) || (s[n] != s[n - 1]);
  }

  // staging sources: pre-swizzled per 16B chunk, LDS dest linear
  const char* xb_src[2];
  #pragma unroll
  for (int i = 0; i < 2; i++) {
    int o = i * 4096 + tid * 16;                 // [0,8192)
    int row = o >> 6;                            // 0..127
    int cc = o & 63;
    int cbyte = ((((cc >> 4) ^ ((row >> 1) & 3)) << 4)) | (cc & 15);
    xb_src[i] = (const char*)xb + (size_t)(m0 + row) * (WIDTH * 2) + h * (BW * 2) + cbyte;
  }
  const char* w_src[2];
  #pragma unroll
  for (int i = 0; i < 2; i++) {
    int o = i * 4096 + tid * 16;                 // [0,8192)
    int g = o >> 12;                             // 0..1
    int jl = (o >> 6) & 63;                      // 0..63
    int cc = o & 63;
    int cbyte = ((((cc >> 4) ^ ((jl >> 1) & 3)) << 4)) | (cc & 15);
    w_src[i] = (const char*)wt + ((size_t)((g * 8 + h) * BW + (j0 + jl))) * (BW * 2) + cbyte;
  }

  // fragment base addresses (loop-invariant; reads use compile-time buf offset)
  uint32_t afb[4], bfb[4];
  #pragma unroll
  for (int mf = 0; mf < 4; mf++) {
    int row = wr * 64 + 16 * mf + lrow;
    afb[mf] = (uint32_t)(row << 6) + (uint32_t)((lkg << 4) ^ (((row >> 1) & 3) << 4));
  }
  #pragma unroll
  for (int q = 0; q < 4; q++) {   // q = g*2+nf
    int g = q >> 1, nf = q & 1;
    int j = wc * 32 + 16 * nf + lrow;
    bfb[q] = 8192u + (uint32_t)(g << 12) + (uint32_t)(j << 6)
           + (uint32_t)((lkg << 4) ^ (((j >> 1) & 3) << 4));
  }

  f32x4 acc[2][4][2];
  #pragma unroll
  for (int g = 0; g < 2; g++)
    #pragma unroll
    for (int mf = 0; mf < 4; mf++)
      #pragma unroll
      for (int nf = 0; nf < 2; nf++)
        acc[g][mf][nf] = (f32x4){0.f, 0.f, 0.f, 0.f};

  // prologue: stage slice p0 into buf0
  {
    const int p0 = (2 * nt + 2) & 15;
    #pragma unroll
    for (int i = 0; i < 2; i++)
      gload_lds16(xb_src[i] + p0 * 64, dsm + i * 4096 + tid * 16);
    #pragma unroll
    for (int i = 0; i < 2; i++)
      gload_lds16(w_src[i] + p0 * 64, dsm + 8192 + i * 4096 + tid * 16);
  }
  __syncthreads();

  #pragma unroll
  for (int st = 0; st < 16; st++) {
    const uint32_t bufb = (uint32_t)(st & 1) << 14;    // compile-time
    if (st < 15) {  // issue next-slice staging BEFORE compute (overlap)
      const uint32_t nb = bufb ^ 16384u;               // compile-time
      const int p = (2 * nt + 3 + st) & 15;            // uniform (SALU)
      #pragma unroll
      for (int i = 0; i < 2; i++)
        gload_lds16(xb_src[i] + p * 64, dsm + nb + i * 4096 + tid * 16);
      #pragma unroll
      for (int i = 0; i < 2; i++)
        gload_lds16(w_src[i] + p * 64, dsm + nb + 8192 + i * 4096 + tid * 16);
    }
    bf16x8 af[4];
    #pragma unroll
    for (int mf = 0; mf < 4; mf++)
      af[mf] = *reinterpret_cast<const bf16x8*>(dsm + bufb + afb[mf]);
    __builtin_amdgcn_s_setprio(1);
    #pragma unroll
    for (int g = 0; g < 2; g++) {
      #pragma unroll
      for (int nf = 0; nf < 2; nf++) {
        bf16x8 bfr = *reinterpret_cast<const bf16x8*>(dsm + bufb + bfb[g * 2 + nf]);
        #pragma unroll
        for (int mf = 0; mf < 4; mf++) {
          acc[g][mf][nf] = __builtin_amdgcn_mfma_f32_16x16x32_bf16(
              af[mf], bfr, acc[g][mf][nf], 0, 0, 0);
        }
      }
    }
    __builtin_amdgcn_s_setprio(0);
    __syncthreads();   // drains issued loads; protects buffer reuse
  }
  // buf0 X = slice 2nt (output cols 0..31), buf1 X = slice 2nt+1 (cols 32..63)

  float* smf = (float*)(dsm + 8192);  // buf0 W region, free after final barrier

  const int jl0 = wc * 32 + lrow;      // nf=0 col (0..63)
  float igb[2], agb[2], cv2[2];
  #pragma unroll
  for (int nf = 0; nf < 2; nf++) {
    int jj = h * BW + j0 + jl0 + 16 * nf;
    igb[nf] = ig_b[jj] * LOG2E; agb[nf] = ag_b[jj] * LOG2E; cv2[nf] = cvec2[jj];
  }

  float segA[2][4], segB[2][4];        // [nf][mf]
  #pragma unroll
  for (int mf = 0; mf < 4; mf++) {
    float A[2] = {1.f, 1.f}, B[2] = {0.f, 0.f};
    int rbase = wr * 64 + 16 * mf + 4 * lkg;
    #pragma unroll
    for (int r = 0; r < 4; r++) {
      int row = rbase + r;
      int n = m0 + row;
      bool rs = resetm[row] != 0;
      uint32_t xsw = (uint32_t)(((row >> 1) & 3) << 4);
      #pragma unroll
      for (int nf = 0; nf < 2; nf++) {   // nf inner: coalesced 128B-line writes
        int jl = jl0 + 16 * nf;
        size_t o = (size_t)n * WIDTH + h * BW + j0 + jl;
        float yig = acc[0][mf][nf][r] + igb[nf];   // log2 domain
        float yag = acc[1][mf][nf][r] + agb[nf];
        float gx = __builtin_amdgcn_rcpf(1.f + exp2f(-yig));
        float ga = __builtin_amdgcn_rcpf(1.f + exp2f(-yag));
        float la2 = -ga * cv2[nf];
        float la_r = __uint_as_float(cvtpk(la2, la2) & 0xffff0000u);  // upper half
        float a = exp2f(la_r);
        float mult = rs ? 1.f
                     : __builtin_amdgcn_sqrtf(fmaxf(1.f - a * a, 0.f));
        int cb = (jl & 31) * 2;
        uint32_t xaddr = ((jl >> 5) ? 16384u : 0u) + (uint32_t)(row << 6)
                       + (uint32_t)(((uint32_t)(cb >> 4) << 4) ^ xsw) + (uint32_t)(cb & 15);
        float xv = bf16_to_f32(*reinterpret_cast<const uint16_t*>(dsm + xaddr));
        float nx = xv * gx * mult;
        uint32_t word = cvtpk(la_r, nx);     // low = la2 bits (exact), high = nx
        float nx_r = __uint_as_float(word & 0xffff0000u);
        lanx[o] = word;
        A[nf] *= a;
        B[nf] = fmaf(a, B[nf], nx_r);
      }
    }
    segA[0][mf] = A[0]; segB[0][mf] = B[0];
    segA[1][mf] = A[1]; segB[1][mf] = B[1];
  }
  // combine across lkg (stride-16 lanes, ascending), then serial across mf
  #pragma unroll
  for (int nf = 0; nf < 2; nf++) {
    #pragma unroll
    for (int mf = 0; mf < 4; mf++) {
      float A = segA[nf][mf], B = segB[nf][mf];
      #pragma unroll
      for (int d = 16; d <= 32; d <<= 1) {
        float pA = __shfl_xor(A, d, 64);
        float pB = __shfl_xor(B, d, 64);
        bool up = (lane & d) != 0;
        B = up ? fmaf(A, pB, B) : fmaf(pA, B, pB);
        A *= pA;
      }
      segA[nf][mf] = A; segB[nf][mf] = B;
    }
    float colA = segA[nf][0], colB = segB[nf][0];
    #pragma unroll
    for (int mf = 1; mf < 4; mf++) {
      colB = fmaf(segA[nf][mf], colB, segB[nf][mf]);
      colA *= segA[nf][mf];
    }
    if (lkg == 0) {
      int clocal = wc * 32 + 16 * nf + lrow;
      smf[wr * 64 + clocal] = colA;
      smf[128 + wr * 64 + clocal] = colB;
    }
  }
  __syncthreads();
  if (tid < BN) {
    float A0 = smf[tid],       B0 = smf[128 + tid];
    float A1 = smf[64 + tid],  B1 = smf[192 + tid];
    float Af = A0 * A1;
    float Bf = fmaf(A1, B0, B1);
    int jj = h * BW + j0 + tid;
    cA[mt * WIDTH + jj] = Af;   // chunk index == mt (BM == CS)
    cB[mt * WIDTH + jj] = Bf;
  }
}

// ---- scan phase B: prefix over chunks (parallel across columns) ----
__global__ void scan_prefix(const float* __restrict__ cA, const float* __restrict__ cB,
                            float* __restrict__ prefix) {
  int c = blockIdx.x * 256 + threadIdx.x;
  float hcur = 0.f;
  for (int i0 = 0; i0 < NCHUNK; i0 += 8) {
    float av[8], bv[8];
    #pragma unroll
    for (int e = 0; e < 8; e++) { av[e] = cA[(i0 + e) * WIDTH + c]; bv[e] = cB[(i0 + e) * WIDTH + c]; }
    #pragma unroll
    for (int e = 0; e < 8; e++) { prefix[(i0 + e) * WIDTH + c] = hcur; hcur = av[e] * hcur + bv[e]; }
  }
}

// ---- scan phase C: apply (packed la2|nx in, f32 out; a = exp2(la2)) ----
__global__ void scan_apply(const uint32_t* __restrict__ lanx,
                           const float* __restrict__ prefix,
                           float* __restrict__ out) {
  int chunk = blockIdx.x;
  int c0 = (blockIdx.y * 256 + threadIdx.x) * 4;
  size_t base = (size_t)chunk * CS * WIDTH + c0;
  float h[4];
  #pragma unroll
  for (int q = 0; q < 4; q++) h[q] = prefix[chunk * WIDTH + c0 + q];
  for (int rb = 0; rb < CS; rb += 4) {
    uint4 v[4];
    #pragma unroll
    for (int e = 0; e < 4; e++)
      v[e] = *reinterpret_cast<const uint4*>(lanx + base + (size_t)(rb + e) * WIDTH);
    #pragma unroll
    for (int e = 0; e < 4; e++) {
      float4 ov;
      h[0] = fmaf(exp2f(bf16_to_f32(v[e].x & 0xffffu)), h[0], bf16_to_f32(v[e].x >> 16)); ov.x = h[0];
      h[1] = fmaf(exp2f(bf16_to_f32(v[e].y & 0xffffu)), h[1], bf16_to_f32(v[e].y >> 16)); ov.y = h[1];
      h[2] = fmaf(exp2f(bf16_to_f32(v[e].z & 0xffffu)), h[2], bf16_to_f32(v[e].z >> 16)); ov.z = h[2];
      h[3] = fmaf(exp2f(bf16_to_f32(v[e].w & 0xffffu)), h[3], bf16_to_f32(v[e].w >> 16)); ov.w = h[3];
      *reinterpret_cast<float4*>(out + base + (size_t)(rb + e) * WIDTH) = ov;
    }
  }
}

extern "C" void kernel_launch(void* const* d_in, const int* in_sizes, int n_in,
                              void* d_out, int out_size, void* d_ws, size_t ws_size,
                              hipStream_t stream) {
  const float* x       = (const float*)d_in[0];
  const int*   s       = (const int*)d_in[1];
  const float* a_param = (const float*)d_in[2];
  const float* ig_w    = (const float*)d_in[3];
  const float* ig_b    = (const float*)d_in[4];
  const float* ag_w    = (const float*)d_in[5];
  const float* ag_b    = (const float*)d_in[6];
  float* out = (float*)d_out;
  char* ws = (char*)d_ws;

  uint32_t* lanx   = (uint32_t*)ws;                     // 134217728 B
  uint16_t* wt     = (uint16_t*)(ws + 134217728);       //   8388608 B
  uint16_t* xb     = (uint16_t*)(ws + 142606336);       //  67108864 B
  float*    cvec2  = (float*)(ws + 209715200);          //     16384 B
  float*    cA     = (float*)(ws + 209731584);          //   1048576 B
  float*    cB     = (float*)(ws + 210780160);          //   1048576 B
  float*    prefix = (float*)(ws + 211828736);          //   1048576 B

  prep_all<<<dim3(12304), 256, 0, stream>>>(x, xb, ig_w, ag_w, wt, a_param, cvec2);
  gates_gemm<<<dim3(4096), 256, 0, stream>>>(xb, s, wt, ig_b, ag_b, cvec2,
                                             lanx, cA, cB);
  scan_prefix<<<dim3(16), 256, 0, stream>>>(cA, cB, prefix);
  scan_apply<<<dim3(NCHUNK, 4), 256, 0, stream>>>(lanx, prefix, out);
}

// Round 18
// 202.223 us; speedup vs baseline: 1.0769x; 1.0769x over previous
//
#include <hip/hip_runtime.h>
#include <hip/hip_bf16.h>
#include <stdint.h>

#define WIDTH 4096
#define NROWS 8192
#define NHEADS 8
#define BW 512
#define CS 128
#define NCHUNK (NROWS/CS)
#define LOG2E 1.4426950408889634f

typedef short bf16x8 __attribute__((ext_vector_type(8)));
typedef float f32x4 __attribute__((ext_vector_type(4)));

#define WAITVM(N) asm volatile("s_waitcnt vmcnt(" #N ")" ::: "memory")
#define WAITLGKM0 asm volatile("s_waitcnt lgkmcnt(0)" ::: "memory")

__device__ __forceinline__ uint32_t rne_bf16(float f) {
  uint32_t u = __float_as_uint(f);
  return (u + 0x7fffu + ((u >> 16) & 1u)) >> 16;
}
__device__ __forceinline__ float bf16_to_f32(uint32_t bits) {
  return __uint_as_float(bits << 16);
}
__device__ __forceinline__ uint32_t cvtpk(float a, float b) {
  uint32_t r;
  asm("v_cvt_pk_bf16_f32 %0, %1, %2" : "=v"(r) : "v"(a), "v"(b));
  return r;
}

__device__ __forceinline__ void gload_lds16(const void* g, void* l) {
  __builtin_amdgcn_global_load_lds(
      (const __attribute__((address_space(1))) void*)g,
      (__attribute__((address_space(3))) void*)l, 16, 0, 0);
}

// ---- fused prep, balanced blocks: weights transpose(+log2e) / x->bf16 / cvec2
__global__ void prep_all(const float* __restrict__ x, uint16_t* __restrict__ xb,
                         const float* __restrict__ ig_w, const float* __restrict__ ag_w,
                         uint16_t* __restrict__ wt,
                         const float* __restrict__ a_param, float* __restrict__ cvec2) {
  __shared__ float tile[32][33];
  const int b = blockIdx.x;
  const int tid = threadIdx.x;
  if (b < 4096) {
    int m  = b >> 8;
    int j0 = ((b >> 4) & 15) * 32;
    int i0 = (b & 15) * 32;
    const float* src = ((m >> 3) ? ag_w : ig_w) + (size_t)(m & 7) * BW * BW;
    int tx = tid & 31, ty = tid >> 5;
    #pragma unroll
    for (int k = 0; k < 4; k++) {
      int i = i0 + ty + 8 * k;
      tile[ty + 8 * k][tx] = src[(size_t)i * BW + (j0 + tx)] * LOG2E;
    }
    __syncthreads();
    #pragma unroll
    for (int k = 0; k < 4; k++) {
      int j = j0 + ty + 8 * k;
      wt[((size_t)m * BW + j) * BW + (i0 + tx)] = (uint16_t)rne_bf16(tile[tx][ty + 8 * k]);
    }
  } else if (b < 12288) {
    size_t i = ((size_t)(b - 4096) * 256 + tid) * 16;
    float4 f0 = *reinterpret_cast<const float4*>(x + i);
    float4 f1 = *reinterpret_cast<const float4*>(x + i + 4);
    float4 f2 = *reinterpret_cast<const float4*>(x + i + 8);
    float4 f3 = *reinterpret_cast<const float4*>(x + i + 12);
    uint4 v0, v1;
    v0.x = cvtpk(f0.x, f0.y); v0.y = cvtpk(f0.z, f0.w);
    v0.z = cvtpk(f1.x, f1.y); v0.w = cvtpk(f1.z, f1.w);
    v1.x = cvtpk(f2.x, f2.y); v1.y = cvtpk(f2.z, f2.w);
    v1.z = cvtpk(f3.x, f3.y); v1.w = cvtpk(f3.z, f3.w);
    *reinterpret_cast<uint4*>(xb + i) = v0;
    *reinterpret_cast<uint4*>(xb + i + 8) = v1;
  } else {
    int i = (b - 12288) * 256 + tid;
    if (i < WIDTH) {
      float v = a_param[i];
      float sp = (v > 15.f) ? v : log1pf(expf(v));
      cvec2[i] = 8.f * sp * LOG2E;
    }
  }
}

// ---- GEMM: dual-gate bf16 MFMA, tile 128x64, BK=32, 256 thr.
//      3-deep pipeline: STAGE slice st+2 at step st; counted vmcnt (never 0
//      in loop); raw s_barrier pairs. Rotated K (mod 16) so output X slices
//      end resident in buf2/buf0 for the epilogue.
#define BM 128
#define BN 64
#define BK 32
// buf j at dsm + j*16384: X [128 rows x 64B] @ +0, W [2][64 x 64B] @ +8192.
// 64B rows: chunk swizzle s(row) = (row>>1)&3 applied to byte bits 4-5.

__global__ __launch_bounds__(256, 3)
void gates_gemm(const uint16_t* __restrict__ xb,
                const int* __restrict__ s,
                const uint16_t* __restrict__ wt,
                const float* __restrict__ ig_b,
                const float* __restrict__ ag_b,
                const float* __restrict__ cvec2,
                uint32_t* __restrict__ lanx,
                float* __restrict__ cA,
                float* __restrict__ cB) {
  __shared__ __align__(16) unsigned char dsm[49152];
  __shared__ unsigned char resetm[BM];

  const int b = blockIdx.x;                    // 0..4095
  const int orig = (b & 7) * 512 + (b >> 3);   // XCD-chunked: one head per XCD
  const int h  = orig >> 9;
  const int rem = orig & 511;
  const int mt = rem >> 3;                     // 0..63
  const int nt = rem & 7;                      // 0..7
  const int m0 = mt * BM;
  const int j0 = nt * BN;

  const int tid = threadIdx.x;
  const int lane = tid & 63;
  const int w = tid >> 6;       // 0..3
  const int wr = w >> 1;        // 0..1 (M: 64-row halves)
  const int wc = w & 1;         // 0..1 (N: 32-col halves)
  const int lrow = lane & 15;
  const int lkg  = lane >> 4;

  if (tid < BM) {
    int n = m0 + tid;
    resetm[tid] = (n == 0) || (s[n] != s[n - 1]);
  }

  // staging sources: pre-swizzled per 16B chunk, LDS dest linear
  const char* xb_src[2];
  #pragma unroll
  for (int i = 0; i < 2; i++) {
    int o = i * 4096 + tid * 16;                 // [0,8192)
    int row = o >> 6;                            // 0..127
    int cc = o & 63;
    int cbyte = ((((cc >> 4) ^ ((row >> 1) & 3)) << 4)) | (cc & 15);
    xb_src[i] = (const char*)xb + (size_t)(m0 + row) * (WIDTH * 2) + h * (BW * 2) + cbyte;
  }
  const char* w_src[2];
  #pragma unroll
  for (int i = 0; i < 2; i++) {
    int o = i * 4096 + tid * 16;                 // [0,8192)
    int g = o >> 12;                             // 0..1
    int jl = (o >> 6) & 63;                      // 0..63
    int cc = o & 63;
    int cbyte = ((((cc >> 4) ^ ((jl >> 1) & 3)) << 4)) | (cc & 15);
    w_src[i] = (const char*)wt + ((size_t)((g * 8 + h) * BW + (j0 + jl))) * (BW * 2) + cbyte;
  }

  // fragment base addresses (loop-invariant)
  uint32_t afb[4], bfb[4];
  #pragma unroll
  for (int mf = 0; mf < 4; mf++) {
    int row = wr * 64 + 16 * mf + lrow;
    afb[mf] = (uint32_t)(row << 6) + (uint32_t)((lkg << 4) ^ (((row >> 1) & 3) << 4));
  }
  #pragma unroll
  for (int q = 0; q < 4; q++) {   // q = g*2+nf
    int g = q >> 1, nf = q & 1;
    int j = wc * 32 + 16 * nf + lrow;
    bfb[q] = 8192u + (uint32_t)(g << 12) + (uint32_t)(j << 6)
           + (uint32_t)((lkg << 4) ^ (((j >> 1) & 3) << 4));
  }

  f32x4 acc[2][4][2];
  #pragma unroll
  for (int g = 0; g < 2; g++)
    #pragma unroll
    for (int mf = 0; mf < 4; mf++)
      #pragma unroll
      for (int nf = 0; nf < 2; nf++)
        acc[g][mf][nf] = (f32x4){0.f, 0.f, 0.f, 0.f};

  // prologue: stage slice0 -> buf0, slice1 -> buf1
  {
    const int p0 = (2 * nt + 2) & 15;
    const int p1 = (2 * nt + 3) & 15;
    #pragma unroll
    for (int i = 0; i < 2; i++)
      gload_lds16(xb_src[i] + p0 * 64, dsm + i * 4096 + tid * 16);
    #pragma unroll
    for (int i = 0; i < 2; i++)
      gload_lds16(w_src[i] + p0 * 64, dsm + 8192 + i * 4096 + tid * 16);
    #pragma unroll
    for (int i = 0; i < 2; i++)
      gload_lds16(xb_src[i] + p1 * 64, dsm + 16384 + i * 4096 + tid * 16);
    #pragma unroll
    for (int i = 0; i < 2; i++)
      gload_lds16(w_src[i] + p1 * 64, dsm + 16384 + 8192 + i * 4096 + tid * 16);
  }

  #pragma unroll
  for (int st = 0; st < 16; st++) {
    const uint32_t bufb = (uint32_t)(st % 3) * 16384u;       // compile-time
    if (st < 14) {   // STAGE slice st+2 into buf[(st+2)%3]
      const uint32_t nb = (uint32_t)((st + 2) % 3) * 16384u; // compile-time
      const int p = (2 * nt + 4 + st) & 15;                  // uniform
      #pragma unroll
      for (int i = 0; i < 2; i++)
        gload_lds16(xb_src[i] + p * 64, dsm + nb + i * 4096 + tid * 16);
      #pragma unroll
      for (int i = 0; i < 2; i++)
        gload_lds16(w_src[i] + p * 64, dsm + nb + 8192 + i * 4096 + tid * 16);
    }
    // wait own slice-st loads only; younger slices stay in flight
    if (st < 14) { WAITVM(8); } else if (st == 14) { WAITVM(4); } else { WAITVM(0); }
    __builtin_amdgcn_s_barrier();          // all waves' slice-st data in LDS
    __builtin_amdgcn_sched_barrier(0);     // no ds_read hoisted above
    bf16x8 af[4];
    #pragma unroll
    for (int mf = 0; mf < 4; mf++)
      af[mf] = *reinterpret_cast<const bf16x8*>(dsm + bufb + afb[mf]);
    __builtin_amdgcn_s_setprio(1);
    #pragma unroll
    for (int g = 0; g < 2; g++) {
      #pragma unroll
      for (int nf = 0; nf < 2; nf++) {
        bf16x8 bfr = *reinterpret_cast<const bf16x8*>(dsm + bufb + bfb[g * 2 + nf]);
        #pragma unroll
        for (int mf = 0; mf < 4; mf++) {
          acc[g][mf][nf] = __builtin_amdgcn_mfma_f32_16x16x32_bf16(
              af[mf], bfr, acc[g][mf][nf], 0, 0, 0);
        }
      }
    }
    __builtin_amdgcn_s_setprio(0);
    WAITLGKM0;                             // own ds_reads drained
    __builtin_amdgcn_sched_barrier(0);     // pin the wait here
    __builtin_amdgcn_s_barrier();          // all reads done -> buffer reusable
  }
  // X slice 2nt (cols 0..31) in buf2 (@32768); slice 2nt+1 (cols 32..63) in buf0.

  float* smf = (float*)(dsm + 16384);  // buf1: idle after the loop

  const int jl0 = wc * 32 + lrow;      // nf=0 col (0..63)
  float igb[2], agb[2], cv2[2];
  #pragma unroll
  for (int nf = 0; nf < 2; nf++) {
    int jj = h * BW + j0 + jl0 + 16 * nf;
    igb[nf] = ig_b[jj] * LOG2E; agb[nf] = ag_b[jj] * LOG2E; cv2[nf] = cvec2[jj];
  }

  float segA[2][4], segB[2][4];        // [nf][mf]
  #pragma unroll
  for (int mf = 0; mf < 4; mf++) {
    float A[2] = {1.f, 1.f}, B[2] = {0.f, 0.f};
    int rbase = wr * 64 + 16 * mf + 4 * lkg;
    #pragma unroll
    for (int r = 0; r < 4; r++) {
      int row = rbase + r;
      int n = m0 + row;
      bool rs = resetm[row] != 0;
      uint32_t xsw = (uint32_t)(((row >> 1) & 3) << 4);
      #pragma unroll
      for (int nf = 0; nf < 2; nf++) {   // nf inner: coalesced 128B-line writes
        int jl = jl0 + 16 * nf;
        size_t o = (size_t)n * WIDTH + h * BW + j0 + jl;
        float yig = acc[0][mf][nf][r] + igb[nf];   // log2 domain
        float yag = acc[1][mf][nf][r] + agb[nf];
        float gx = __builtin_amdgcn_rcpf(1.f + exp2f(-yig));
        float ga = __builtin_amdgcn_rcpf(1.f + exp2f(-yag));
        float la2 = -ga * cv2[nf];
        float la_r = __uint_as_float(cvtpk(la2, la2) & 0xffff0000u);
        float a = exp2f(la_r);
        float mult = rs ? 1.f
                     : __builtin_amdgcn_sqrtf(fmaxf(1.f - a * a, 0.f));
        int cb = (jl & 31) * 2;
        uint32_t xaddr = ((jl >> 5) ? 0u : 32768u) + (uint32_t)(row << 6)
                       + (uint32_t)(((uint32_t)(cb >> 4) << 4) ^ xsw) + (uint32_t)(cb & 15);
        float xv = bf16_to_f32(*reinterpret_cast<const uint16_t*>(dsm + xaddr));
        float nx = xv * gx * mult;
        uint32_t word = cvtpk(la_r, nx);     // low = la2 bits (exact), high = nx
        float nx_r = __uint_as_float(word & 0xffff0000u);
        lanx[o] = word;
        A[nf] *= a;
        B[nf] = fmaf(a, B[nf], nx_r);
      }
    }
    segA[0][mf] = A[0]; segB[0][mf] = B[0];
    segA[1][mf] = A[1]; segB[1][mf] = B[1];
  }
  // combine across lkg (stride-16 lanes, ascending), then serial across mf
  #pragma unroll
  for (int nf = 0; nf < 2; nf++) {
    #pragma unroll
    for (int mf = 0; mf < 4; mf++) {
      float A = segA[nf][mf], B = segB[nf][mf];
      #pragma unroll
      for (int d = 16; d <= 32; d <<= 1) {
        float pA = __shfl_xor(A, d, 64);
        float pB = __shfl_xor(B, d, 64);
        bool up = (lane & d) != 0;
        B = up ? fmaf(A, pB, B) : fmaf(pA, B, pB);
        A *= pA;
      }
      segA[nf][mf] = A; segB[nf][mf] = B;
    }
    float colA = segA[nf][0], colB = segB[nf][0];
    #pragma unroll
    for (int mf = 1; mf < 4; mf++) {
      colB = fmaf(segA[nf][mf], colB, segB[nf][mf]);
      colA *= segA[nf][mf];
    }
    if (lkg == 0) {
      int clocal = wc * 32 + 16 * nf + lrow;
      smf[wr * 64 + clocal] = colA;
      smf[128 + wr * 64 + clocal] = colB;
    }
  }
  __syncthreads();
  if (tid < BN) {
    float A0 = smf[tid],       B0 = smf[128 + tid];
    float A1 = smf[64 + tid],  B1 = smf[192 + tid];
    float Af = A0 * A1;
    float Bf = fmaf(A1, B0, B1);
    int jj = h * BW + j0 + tid;
    cA[mt * WIDTH + jj] = Af;   // chunk index == mt (BM == CS)
    cB[mt * WIDTH + jj] = Bf;
  }
}

// ---- scan phase B: prefix over chunks (parallel across columns) ----
__global__ void scan_prefix(const float* __restrict__ cA, const float* __restrict__ cB,
                            float* __restrict__ prefix) {
  int c = blockIdx.x * 256 + threadIdx.x;
  float hcur = 0.f;
  for (int i0 = 0; i0 < NCHUNK; i0 += 8) {
    float av[8], bv[8];
    #pragma unroll
    for (int e = 0; e < 8; e++) { av[e] = cA[(i0 + e) * WIDTH + c]; bv[e] = cB[(i0 + e) * WIDTH + c]; }
    #pragma unroll
    for (int e = 0; e < 8; e++) { prefix[(i0 + e) * WIDTH + c] = hcur; hcur = av[e] * hcur + bv[e]; }
  }
}

// ---- scan phase C: apply (packed la2|nx in, f32 out; a = exp2(la2)) ----
__global__ void scan_apply(const uint32_t* __restrict__ lanx,
                           const float* __restrict__ prefix,
                           float* __restrict__ out) {
  int chunk = blockIdx.x;
  int c0 = (blockIdx.y * 256 + threadIdx.x) * 4;
  size_t base = (size_t)chunk * CS * WIDTH + c0;
  float h[4];
  #pragma unroll
  for (int q = 0; q < 4; q++) h[q] = prefix[chunk * WIDTH + c0 + q];
  for (int rb = 0; rb < CS; rb += 4) {
    uint4 v[4];
    #pragma unroll
    for (int e = 0; e < 4; e++)
      v[e] = *reinterpret_cast<const uint4*>(lanx + base + (size_t)(rb + e) * WIDTH);
    #pragma unroll
    for (int e = 0; e < 4; e++) {
      float4 ov;
      h[0] = fmaf(exp2f(bf16_to_f32(v[e].x & 0xffffu)), h[0], bf16_to_f32(v[e].x >> 16)); ov.x = h[0];
      h[1] = fmaf(exp2f(bf16_to_f32(v[e].y & 0xffffu)), h[1], bf16_to_f32(v[e].y >> 16)); ov.y = h[1];
      h[2] = fmaf(exp2f(bf16_to_f32(v[e].z & 0xffffu)), h[2], bf16_to_f32(v[e].z >> 16)); ov.z = h[2];
      h[3] = fmaf(exp2f(bf16_to_f32(v[e].w & 0xffffu)), h[3], bf16_to_f32(v[e].w >> 16)); ov.w = h[3];
      *reinterpret_cast<float4*>(out + base + (size_t)(rb + e) * WIDTH) = ov;
    }
  }
}

extern "C" void kernel_launch(void* const* d_in, const int* in_sizes, int n_in,
                              void* d_out, int out_size, void* d_ws, size_t ws_size,
                              hipStream_t stream) {
  const float* x       = (const float*)d_in[0];
  const int*   s       = (const int*)d_in[1];
  const float* a_param = (const float*)d_in[2];
  const float* ig_w    = (const float*)d_in[3];
  const float* ig_b    = (const float*)d_in[4];
  const float* ag_w    = (const float*)d_in[5];
  const float* ag_b    = (const float*)d_in[6];
  float* out = (float*)d_out;
  char* ws = (char*)d_ws;

  uint32_t* lanx   = (uint32_t*)ws;                     // 134217728 B
  uint16_t* wt     = (uint16_t*)(ws + 134217728);       //   8388608 B
  uint16_t* xb     = (uint16_t*)(ws + 142606336);       //  67108864 B
  float*    cvec2  = (float*)(ws + 209715200);          //     16384 B
  float*    cA     = (float*)(ws + 209731584);          //   1048576 B
  float*    cB     = (float*)(ws + 210780160);          //   1048576 B
  float*    prefix = (float*)(ws + 211828736);          //   1048576 B

  prep_all<<<dim3(12304), 256, 0, stream>>>(x, xb, ig_w, ag_w, wt, a_param, cvec2);
  gates_gemm<<<dim3(4096), 256, 0, stream>>>(xb, s, wt, ig_b, ag_b, cvec2,
                                             lanx, cA, cB);
  scan_prefix<<<dim3(16), 256, 0, stream>>>(cA, cB, prefix);
  scan_apply<<<dim3(NCHUNK, 4), 256, 0, stream>>>(lanx, prefix, out);
}